// Round 1
// baseline (23131.435 us; speedup 1.0000x reference)
//
#include <hip/hip_runtime.h>
#include <hip/hip_fp16.h>

#define B_ 128
#define S_ 512
#define H_ 256

typedef _Float16 h2_t __attribute__((ext_vector_type(2)));

__device__ __forceinline__ float fdot2(unsigned int a, unsigned int b, float c) {
#if __has_builtin(__builtin_amdgcn_fdot2)
    return __builtin_amdgcn_fdot2(__builtin_bit_cast(h2_t, a), __builtin_bit_cast(h2_t, b), c, false);
#else
    h2_t ha = __builtin_bit_cast(h2_t, a), hb = __builtin_bit_cast(h2_t, b);
    return c + (float)ha[0]*(float)hb[0] + (float)ha[1]*(float)hb[1];
#endif
}

__device__ __forceinline__ unsigned int pk16(float a, float b) {
    auto h = __builtin_amdgcn_cvt_pkrtz(a, b);
    return __builtin_bit_cast(unsigned int, h);
}

__device__ __forceinline__ float rcp_(float x) {
#if __has_builtin(__builtin_amdgcn_rcpf)
    return __builtin_amdgcn_rcpf(x);
#else
    return 1.0f / x;
#endif
}

__device__ __forceinline__ float sigm(float x) { return rcp_(1.0f + __expf(-x)); }
__device__ __forceinline__ float tanh_(float x) {
    float e = __expf(2.0f * x);
    return 1.0f - 2.0f * rcp_(e + 1.0f);
}

// ---- prep: pack weight matrices to f16 pairs, layout [k4][j] (uint2 = 4 halves of row j, cols 4k4..4k4+3) ----
__global__ __launch_bounds__(256) void prep_kernel(
    const float* __restrict__ encWhh, const float* __restrict__ decWih,
    const float* __restrict__ decWhh, const float* __restrict__ W2w,
    uint2* __restrict__ We4, uint2* __restrict__ Wi4, uint2* __restrict__ Wh4, uint2* __restrict__ W24)
{
    int id = blockIdx.x * 256 + threadIdx.x;
    if (id < 3 * 65536) {
        int mat = id >> 16, local = id & 65535;
        int j = local & 1023, k4 = local >> 10;
        const float* src = mat == 0 ? encWhh : (mat == 1 ? decWih : decWhh);
        uint2* dst = mat == 0 ? We4 : (mat == 1 ? Wi4 : Wh4);
        float4 v = *(const float4*)(src + (size_t)j * 256 + k4 * 4);
        dst[k4 * 1024 + j] = make_uint2(pk16(v.x, v.y), pk16(v.z, v.w));
    } else {
        int local = id - 3 * 65536;
        if (local < 64 * 256) {
            int m = local & 255, k4 = local >> 8;
            float4 v = *(const float4*)(W2w + (size_t)m * 256 + k4 * 4);
            W24[k4 * 256 + m] = make_uint2(pk16(v.x, v.y), pk16(v.z, v.w));
        }
    }
}

// ---- GEMM: C[M][N](f16) = A[M][256] * Bw[N][256]^T + bias ; BM=64 BN=128 BK=16, 256 thr ----
template<int A_IS_F16>
__global__ __launch_bounds__(256) void gemm_kernel(
    const void* __restrict__ A_, const float* __restrict__ Bw,
    const float* __restrict__ bias, unsigned short* __restrict__ C, int N)
{
    __shared__ float As[16][68];
    __shared__ float Bs[16][132];
    const int t = threadIdx.x;
    const int row0 = blockIdx.y * 64, col0 = blockIdx.x * 128;
    const int ty = t >> 4, tx = t & 15;
    const int lm = t & 63, lkq = t >> 6;
    const int ln = t & 127, lkq2 = t >> 7;
    float acc[4][8] = {};
    for (int k0 = 0; k0 < 256; k0 += 16) {
        float4 av;
        if constexpr (A_IS_F16) {
            const unsigned short* A = (const unsigned short*)A_;
            uint2 ha = *(const uint2*)(A + (size_t)(row0 + lm) * 256 + k0 + lkq * 4);
            h2_t h0 = __builtin_bit_cast(h2_t, ha.x);
            h2_t h1 = __builtin_bit_cast(h2_t, ha.y);
            av = make_float4((float)h0[0], (float)h0[1], (float)h1[0], (float)h1[1]);
        } else {
            av = *(const float4*)((const float*)A_ + (size_t)(row0 + lm) * 256 + k0 + lkq * 4);
        }
        const float* bp = Bw + (size_t)(col0 + ln) * 256 + k0 + lkq2 * 8;
        float4 bv0 = *(const float4*)bp;
        float4 bv1 = *(const float4*)(bp + 4);
        __syncthreads();
        As[lkq * 4 + 0][lm] = av.x;
        As[lkq * 4 + 1][lm] = av.y;
        As[lkq * 4 + 2][lm] = av.z;
        As[lkq * 4 + 3][lm] = av.w;
        Bs[lkq2 * 8 + 0][ln] = bv0.x;
        Bs[lkq2 * 8 + 1][ln] = bv0.y;
        Bs[lkq2 * 8 + 2][ln] = bv0.z;
        Bs[lkq2 * 8 + 3][ln] = bv0.w;
        Bs[lkq2 * 8 + 4][ln] = bv1.x;
        Bs[lkq2 * 8 + 5][ln] = bv1.y;
        Bs[lkq2 * 8 + 6][ln] = bv1.z;
        Bs[lkq2 * 8 + 7][ln] = bv1.w;
        __syncthreads();
        #pragma unroll
        for (int kk = 0; kk < 16; ++kk) {
            float4 a = *(float4*)&As[kk][ty * 4];
            float4 b0 = *(float4*)&Bs[kk][tx * 8];
            float4 b1 = *(float4*)&Bs[kk][tx * 8 + 4];
            float ar[4] = {a.x, a.y, a.z, a.w};
            float br[8] = {b0.x, b0.y, b0.z, b0.w, b1.x, b1.y, b1.z, b1.w};
            #pragma unroll
            for (int i = 0; i < 4; ++i)
                #pragma unroll
                for (int j = 0; j < 8; ++j)
                    acc[i][j] = fmaf(ar[i], br[j], acc[i][j]);
        }
    }
    float bv[8];
    #pragma unroll
    for (int j = 0; j < 8; ++j) bv[j] = bias[col0 + tx * 8 + j];
    #pragma unroll
    for (int i = 0; i < 4; ++i) {
        unsigned int w0 = pk16(acc[i][0] + bv[0], acc[i][1] + bv[1]);
        unsigned int w1 = pk16(acc[i][2] + bv[2], acc[i][3] + bv[3]);
        unsigned int w2 = pk16(acc[i][4] + bv[4], acc[i][5] + bv[5]);
        unsigned int w3 = pk16(acc[i][6] + bv[6], acc[i][7] + bv[7]);
        *(uint4*)(C + (size_t)(row0 + ty * 4 + i) * N + col0 + tx * 8) = make_uint4(w0, w1, w2, w3);
    }
}

// ---- encoder: 1 block per batch, 1024 thr; z_j via dot2 from packed-f16 Whh stream + Xproj(f16) ----
__global__ __launch_bounds__(1024) void encoder_kernel(
    const unsigned short* __restrict__ Xproj, const uint2* __restrict__ We4,
    float* __restrict__ hfin, float* __restrict__ cfin, unsigned short* __restrict__ enc_h)
{
    const int b = blockIdx.x, t = threadIdx.x;
    __shared__ __align__(16) float zs[1024];
    __shared__ __align__(16) float hf[256];
    __shared__ __align__(16) unsigned int hh2[128];
    if (t < 256) hf[t] = 0.0f;
    if (t < 128) hh2[t] = 0u;
    float c_reg = 0.0f;
    __syncthreads();
    const unsigned short* xp = Xproj + (size_t)b * 512 * 1024 + t;
    const uint2* w = We4 + t;
    for (int step = 0; step < 512; ++step) {
        float acc = __half2float(__ushort_as_half(xp[0]));
        #pragma unroll 8
        for (int k4 = 0; k4 < 64; ++k4) {
            uint2 wv = w[k4 * 1024];
            uint2 hv = *(const uint2*)&hh2[k4 * 2];
            acc = fdot2(wv.x, hv.x, acc);
            acc = fdot2(wv.y, hv.y, acc);
        }
        zs[t] = acc;
        __syncthreads();
        if (t < 256) {
            float ig = sigm(zs[t]);
            float fg = sigm(zs[t + 256]);
            float gg = tanh_(zs[t + 512]);
            float og = sigm(zs[t + 768]);
            c_reg = fg * c_reg + ig * gg;
            float h = og * tanh_(c_reg);
            hf[t] = h;
            float hnb = __shfl_down(h, 1);
            if ((t & 1) == 0) hh2[t >> 1] = pk16(h, hnb);
            enc_h[(size_t)(b * 512 + step) * 256 + t] = __half_as_ushort(__float2half_rn(h));
        }
        __syncthreads();
        xp += 1024;
    }
    if (t < 256) { hfin[b * 256 + t] = hf[t]; cfin[b * 256 + t] = c_reg; }
}

// ---- transpose enc_out [b][s][h] f16 -> encT2 [b][h][s2] packed s-pairs ----
__global__ __launch_bounds__(256) void transpose_kernel(
    const unsigned short* __restrict__ enc_h, unsigned int* __restrict__ encT2)
{
    __shared__ unsigned short tile[64][72];
    const int b = blockIdx.y, h0 = blockIdx.x * 64;
    const int t = threadIdx.x;
    const int sl = t >> 2, hg = (t & 3) * 16;
    const int hl = t >> 2, sg = (t & 3) * 8;
    for (int s0 = 0; s0 < 512; s0 += 64) {
        const unsigned short* src = enc_h + ((size_t)(b * 512 + s0 + sl) * 256 + h0 + hg);
        uint4 v0 = *(const uint4*)src;
        uint4 v1 = *(const uint4*)(src + 8);
        __syncthreads();
        *(uint4*)&tile[sl][hg] = v0;
        *(uint4*)&tile[sl][hg + 8] = v1;
        __syncthreads();
        unsigned int* dst = encT2 + ((size_t)b * 256 + h0 + hl) * 256 + (s0 >> 1) + sg;
        #pragma unroll
        for (int i = 0; i < 8; ++i) {
            int s2 = sg + i;
            dst[i] = (unsigned int)tile[2 * s2][hl] | ((unsigned int)tile[2 * s2 + 1][hl] << 16);
        }
    }
}

// ---- decoder: 1 block per batch, full 512-step pointer loop ----
__global__ __launch_bounds__(1024) void decoder_kernel(
    const uint2* __restrict__ Wi4, const uint2* __restrict__ Wh4, const uint2* __restrict__ W24,
    const float* __restrict__ dec_b, const float* __restrict__ W2b, const float* __restrict__ vtw,
    const float* __restrict__ hfin, const float* __restrict__ cfin,
    const unsigned short* __restrict__ proj_h, const unsigned int* __restrict__ encT2,
    float* __restrict__ out)
{
    const int b = blockIdx.x, t = threadIdx.x;
    __shared__ __align__(16) float zs[1024];
    __shared__ __align__(16) float hf0[256];
    __shared__ __align__(16) unsigned int hh2[128];
    __shared__ __align__(16) unsigned int din2[128];
    __shared__ __align__(16) float qc2[256];
    __shared__ __align__(16) float m2vt[256];
    __shared__ __align__(16) unsigned int p2[256];
    __shared__ float wred[16], wred2[16], svt[2];

    const float bj = dec_b[t];
    const float w2b_r = (t < 256) ? W2b[t] : 0.0f;
    float c_reg = (t < 256) ? cfin[b * 256 + t] : 0.0f;
    if (t < 256) { hf0[t] = hfin[b * 256 + t]; m2vt[t] = -2.0f * vtw[t]; }
    if (t < 128) din2[t] = 0u;
    if (t < 2) { float s = 0.f; for (int k = 0; k < 128; ++k) s += vtw[t * 128 + k]; svt[t] = s; }
    __syncthreads();
    if (t < 128) hh2[t] = pk16(hf0[2 * t], hf0[2 * t + 1]);
    __syncthreads();

    const int s_idx = t >> 1, half = t & 1;
    const int lane = t & 63, wave = t >> 6;
    const unsigned short* projp = proj_h + (size_t)b * 512 * 256 + (size_t)s_idx * 256 + half * 128;
    const unsigned int* dinrow = encT2 + (size_t)b * 65536 + (size_t)(t >> 2) * 256 + (t & 3) * 64;
    float* outp = out + (size_t)b * 512 * 512;
    const uint2* wi = Wi4 + t;
    const uint2* wh = Wh4 + t;
    const uint2* w2 = W24 + t;

    for (int step = 0; step < 512; ++step) {
        // A: z = dec_b + Wih*din + Whh*h
        float acc = bj;
        #pragma unroll 8
        for (int k4 = 0; k4 < 64; ++k4) {
            uint2 wv = wi[k4 * 1024];
            uint2 dv = *(const uint2*)&din2[k4 * 2];
            acc = fdot2(wv.x, dv.x, acc);
            acc = fdot2(wv.y, dv.y, acc);
        }
        #pragma unroll 8
        for (int k4 = 0; k4 < 64; ++k4) {
            uint2 wv = wh[k4 * 1024];
            uint2 hv = *(const uint2*)&hh2[k4 * 2];
            acc = fdot2(wv.x, hv.x, acc);
            acc = fdot2(wv.y, hv.y, acc);
        }
        zs[t] = acc;
        __syncthreads();
        // B: gates
        if (t < 256) {
            float ig = sigm(zs[t]);
            float fg = sigm(zs[t + 256]);
            float gg = tanh_(zs[t + 512]);
            float og = sigm(zs[t + 768]);
            c_reg = fg * c_reg + ig * gg;
            float h = og * tanh_(c_reg);
            float hnb = __shfl_down(h, 1);
            if ((t & 1) == 0) hh2[t >> 1] = pk16(h, hnb);
        }
        __syncthreads();
        // C: q = W2*h + b ; store 2q
        if (t < 256) {
            float q = w2b_r;
            #pragma unroll 8
            for (int k4 = 0; k4 < 64; ++k4) {
                uint2 wv = w2[k4 * 256];
                uint2 hv = *(const uint2*)&hh2[k4 * 2];
                q = fdot2(wv.x, hv.x, q);
                q = fdot2(wv.y, hv.y, q);
            }
            qc2[t] = 2.0f * q;
        }
        __syncthreads();
        // D: u[s] = sum_h vt*tanh(proj+q) ; tanh = 1 - 2/(1+e^{2y})
        float part = 0.0f;
        #pragma unroll 2
        for (int i8 = 0; i8 < 16; ++i8) {
            uint4 pv = *(const uint4*)(projp + i8 * 8);
            const float* qb = &qc2[half * 128 + i8 * 8];
            const float* vb = &m2vt[half * 128 + i8 * 8];
            float4 q0 = *(const float4*)qb;
            float4 q1 = *(const float4*)(qb + 4);
            float4 v0 = *(const float4*)vb;
            float4 v1 = *(const float4*)(vb + 4);
            h2_t p0 = __builtin_bit_cast(h2_t, pv.x);
            h2_t p1 = __builtin_bit_cast(h2_t, pv.y);
            h2_t p2h = __builtin_bit_cast(h2_t, pv.z);
            h2_t p3 = __builtin_bit_cast(h2_t, pv.w);
            float pf[8] = {(float)p0[0], (float)p0[1], (float)p1[0], (float)p1[1],
                           (float)p2h[0], (float)p2h[1], (float)p3[0], (float)p3[1]};
            float qf[8] = {q0.x, q0.y, q0.z, q0.w, q1.x, q1.y, q1.z, q1.w};
            float vf[8] = {v0.x, v0.y, v0.z, v0.w, v1.x, v1.y, v1.z, v1.w};
            #pragma unroll
            for (int j = 0; j < 8; ++j) {
                float e = __expf(fmaf(2.0f, pf[j], qf[j]));
                float r = rcp_(1.0f + e);
                part = fmaf(vf[j], r, part);
            }
        }
        part += svt[half];
        part += __shfl_xor(part, 1);   // both pair-lanes hold u[s]
        // softmax: max
        float wm = part;
        #pragma unroll
        for (int off = 1; off < 64; off <<= 1) wm = fmaxf(wm, __shfl_xor(wm, off));
        if (lane == 0) wred[wave] = wm;
        __syncthreads();
        float gmax = wred[0];
        #pragma unroll
        for (int k = 1; k < 16; ++k) gmax = fmaxf(gmax, wred[k]);
        float e_s = __expf(part - gmax);
        float wsm = e_s;   // duplicates -> 2x sum
        #pragma unroll
        for (int off = 1; off < 64; off <<= 1) wsm += __shfl_xor(wsm, off);
        if (lane == 0) wred2[wave] = wsm;
        float e_nx = __shfl_down(e_s, 2);
        if ((t & 3) == 0) p2[t >> 2] = pk16(e_s, e_nx);
        __syncthreads();
        float gsum2 = wred2[0];
        #pragma unroll
        for (int k = 1; k < 16; ++k) gsum2 += wred2[k];
        float rs = 2.0f * rcp_(gsum2);   // = 1/sum(e)
        if (half == 0) outp[(size_t)step * 512 + s_idx] = e_s * rs;
        // F: din[m] = (sum_s e_s * enc_out[s][m]) / sum(e)
        float dp = 0.0f;
        #pragma unroll 4
        for (int i4 = 0; i4 < 16; ++i4) {
            uint4 ev = *(const uint4*)(dinrow + i4 * 4);
            uint4 pv2 = *(const uint4*)&p2[(t & 3) * 64 + i4 * 4];
            dp = fdot2(ev.x, pv2.x, dp);
            dp = fdot2(ev.y, pv2.y, dp);
            dp = fdot2(ev.z, pv2.z, dp);
            dp = fdot2(ev.w, pv2.w, dp);
        }
        dp += __shfl_xor(dp, 1);
        dp += __shfl_xor(dp, 2);
        float dval = dp * rs;
        float dnx = __shfl_down(dval, 4);
        if ((t & 7) == 0) din2[t >> 3] = pk16(dval, dnx);
        __syncthreads();
    }
}

extern "C" void kernel_launch(void* const* d_in, const int* in_sizes, int n_in,
                              void* d_out, int out_size, void* d_ws, size_t ws_size,
                              hipStream_t stream) {
    const float* x      = (const float*)d_in[0];
    const float* encWih = (const float*)d_in[1];
    const float* encWhh = (const float*)d_in[2];
    const float* enc_b  = (const float*)d_in[3];
    const float* decWih = (const float*)d_in[4];
    const float* decWhh = (const float*)d_in[5];
    const float* dec_bp = (const float*)d_in[6];
    const float* W1w    = (const float*)d_in[7];
    const float* W1b    = (const float*)d_in[8];
    const float* W2w    = (const float*)d_in[9];
    const float* W2bp   = (const float*)d_in[10];
    const float* vtw    = (const float*)d_in[11];

    char* ws = (char*)d_ws;
    uint2* We4 = (uint2*)(ws);
    uint2* Wi4 = (uint2*)(ws + 524288);
    uint2* Wh4 = (uint2*)(ws + 1048576);
    uint2* W24 = (uint2*)(ws + 1572864);
    unsigned short* enc_h  = (unsigned short*)(ws + 1703936);
    unsigned int*   encT2  = (unsigned int*)(ws + 35258368);
    unsigned short* proj_h = (unsigned short*)(ws + 68812800);
    float* hfin = (float*)(ws + 102367232);
    float* cfin = (float*)(ws + 102498304);

    unsigned short* Xproj = (unsigned short*)d_out;  // f16 [65536][1024], consumed before decoder overwrites

    prep_kernel<<<832, 256, 0, stream>>>(encWhh, decWih, decWhh, W2w, We4, Wi4, Wh4, W24);
    gemm_kernel<0><<<dim3(8, 1024), 256, 0, stream>>>(x, encWih, enc_b, Xproj, 1024);
    encoder_kernel<<<128, 1024, 0, stream>>>(Xproj, We4, hfin, cfin, enc_h);
    transpose_kernel<<<dim3(4, 128), 256, 0, stream>>>(enc_h, encT2);
    gemm_kernel<1><<<dim3(2, 1024), 256, 0, stream>>>(enc_h, W1w, W1b, proj_h, 256);
    decoder_kernel<<<128, 1024, 0, stream>>>(Wi4, Wh4, W24, dec_bp, W2bp, vtw,
                                             hfin, cfin, proj_h, encT2, (float*)d_out);
}